// Round 1
// baseline (763.681 us; speedup 1.0000x reference)
//
#include <hip/hip_runtime.h>
#include <hip/hip_bf16.h>

#define SS 2048
#define HH 1024
#define NHH 16
#define HDD 64

__device__ __forceinline__ void tetra(float t, float* c) {
    float a = 1.f / (1.f + __expf(-t));
    float na = 1.f - a;
    float nei = 1.f - (a + na);
    nei = fminf(fmaxf(nei, 0.f), 1.f);
    c[0] = a; c[1] = na; c[2] = a * na; c[3] = nei;
}

// Kernel 1: per (b,s) row, compute the 32 Q-cols and 32 K-cols actually used,
// then the tetra features. qf gets score scales folded in (1/8 and 0.1).
__global__ __launch_bounds__(256) void qk_feat_kernel(
    const float* __restrict__ x,
    const float* __restrict__ Wq, const float* __restrict__ bq,
    const float* __restrict__ Wk, const float* __restrict__ bk,
    float* __restrict__ qf, float* __restrict__ kf)
{
    __shared__ float xs[HH];
    __shared__ float part[64][4];
    __shared__ float yv[64];
    int tid = threadIdx.x;
    int m = blockIdx.x;               // b*S + s
    int b = m >> 11, s = m & 2047;

    ((float4*)xs)[tid] = ((const float4*)(x + (size_t)m * HH))[tid];
    __syncthreads();

    int o = tid >> 2, p = tid & 3;    // output o (0..63), partial p (0..3)
    int oo = o & 31;
    int h = oo >> 1, hd = (oo & 1) * 2;
    int j = h * HDD + hd;
    const float* W; float bias;
    if (o < 32) { W = Wq; bias = bq[j]; } else { W = Wk; bias = bk[j]; }

    const float4* wr = (const float4*)(W + (size_t)j * HH + p * 256);
    const float4* xr = (const float4*)(xs + p * 256);
    float sum = (p == 0) ? bias : 0.f;
    #pragma unroll 8
    for (int i = 0; i < 64; i++) {
        float4 w4 = wr[i], x4 = xr[i];
        sum += w4.x * x4.x + w4.y * x4.y + w4.z * x4.z + w4.w * x4.w;
    }
    part[o][p] = sum;
    __syncthreads();
    if (tid < 64) yv[tid] = part[tid][0] + part[tid][1] + part[tid][2] + part[tid][3];
    __syncthreads();

    if (tid < 16) {
        int hh = tid;
        float qa[4], qb[4], ka[4], kb[4];
        tetra(yv[2 * hh], qa);
        tetra(yv[2 * hh + 1], qb);
        tetra(yv[32 + 2 * hh], ka);
        tetra(yv[32 + 2 * hh + 1], kb);
        size_t base = ((size_t)(b * NHH + hh) * SS + s) * 8;
        const float inv8 = 0.125f;
        #pragma unroll
        for (int c = 0; c < 4; c++) {
            qf[base + c]     = qa[c] * inv8;
            qf[base + 4 + c] = qb[c] * 0.1f;
            kf[base + c]     = ka[c];
            kf[base + 4 + c] = kb[c];
        }
    }
}

// Kernel 2/4: C[m][n] = sum_k A[m][k]*W[n][k] + bias[n]; M=grid.y*128, N=1024, K=1024.
// 128x128 block tile, BK=16, 8x8 per thread.
__global__ __launch_bounds__(256) void gemm_xt_kernel(
    const float* __restrict__ A, const float* __restrict__ W,
    const float* __restrict__ bias, float* __restrict__ C)
{
    __shared__ float As[16][128];
    __shared__ float Wt[16][128];
    int tid = threadIdx.x;
    int m0 = blockIdx.y * 128, n0 = blockIdx.x * 128;
    int ty = tid >> 4, tx = tid & 15;   // 16x16 thread grid, 8x8 each

    int lr = tid >> 1;                  // load row 0..127
    int lk = (tid & 1) * 8;             // k offset 0 or 8
    const float* Aptr = A + (size_t)(m0 + lr) * HH + lk;
    const float* Wptr = W + (size_t)(n0 + lr) * HH + lk;

    float acc[8][8] = {};

    for (int k0 = 0; k0 < HH; k0 += 16) {
        float4 a0 = *(const float4*)(Aptr + k0);
        float4 a1 = *(const float4*)(Aptr + k0 + 4);
        float4 w0 = *(const float4*)(Wptr + k0);
        float4 w1 = *(const float4*)(Wptr + k0 + 4);
        __syncthreads();
        As[lk + 0][lr] = a0.x; As[lk + 1][lr] = a0.y; As[lk + 2][lr] = a0.z; As[lk + 3][lr] = a0.w;
        As[lk + 4][lr] = a1.x; As[lk + 5][lr] = a1.y; As[lk + 6][lr] = a1.z; As[lk + 7][lr] = a1.w;
        Wt[lk + 0][lr] = w0.x; Wt[lk + 1][lr] = w0.y; Wt[lk + 2][lr] = w0.z; Wt[lk + 3][lr] = w0.w;
        Wt[lk + 4][lr] = w1.x; Wt[lk + 5][lr] = w1.y; Wt[lk + 6][lr] = w1.z; Wt[lk + 7][lr] = w1.w;
        __syncthreads();
        #pragma unroll
        for (int kk = 0; kk < 16; kk++) {
            float av[8], bv[8];
            *(float4*)&av[0] = *(float4*)&As[kk][ty * 8];
            *(float4*)&av[4] = *(float4*)&As[kk][ty * 8 + 4];
            *(float4*)&bv[0] = *(float4*)&Wt[kk][tx * 8];
            *(float4*)&bv[4] = *(float4*)&Wt[kk][tx * 8 + 4];
            #pragma unroll
            for (int i = 0; i < 8; i++)
                #pragma unroll
                for (int jj = 0; jj < 8; jj++)
                    acc[i][jj] += av[i] * bv[jj];
        }
    }

    float4 bb0 = *(const float4*)(bias + n0 + tx * 8);
    float4 bb1 = *(const float4*)(bias + n0 + tx * 8 + 4);
    #pragma unroll
    for (int i = 0; i < 8; i++) {
        int mrow = m0 + ty * 8 + i;
        float4 c0 = { acc[i][0] + bb0.x, acc[i][1] + bb0.y, acc[i][2] + bb0.z, acc[i][3] + bb0.w };
        float4 c1 = { acc[i][4] + bb1.x, acc[i][5] + bb1.y, acc[i][6] + bb1.z, acc[i][7] + bb1.w };
        *(float4*)(C + (size_t)mrow * HH + n0 + tx * 8) = c0;
        *(float4*)(C + (size_t)mrow * HH + n0 + tx * 8 + 4) = c1;
    }
}

// Kernel 3: flash-style attention. Scores bounded in [0,~0.7] -> plain exp, no max.
// Block: one (b,h), 128 Q-rows. Loop over 64-row KV tiles.
#define BQ 128
__global__ __launch_bounds__(256) void attn_kernel(
    const float* __restrict__ qf, const float* __restrict__ kf,
    const float* __restrict__ V, float* __restrict__ O)
{
    __shared__ float kfs[64][8];
    __shared__ float Vs[64][68];        // pad 64->68 to break bank aliasing
    __shared__ float ps[64][BQ + 4];    // [t][row], stride 132 keeps 16B alignment

    int tid = threadIdx.x;
    int bh = blockIdx.y;
    int b = bh >> 4, h = bh & 15;
    int s0 = blockIdx.x * BQ;

    // score phase mapping: 2 threads per row, 32 t's each
    int srow = tid >> 1;
    int thalf = (tid & 1) * 32;
    const float* qrow = qf + ((size_t)bh * SS + s0 + srow) * 8;
    float4 qlo = *(const float4*)qrow;
    float4 qhi = *(const float4*)(qrow + 4);

    // PV mapping: thread owns 8 rows x 4 d
    int rg = tid >> 4;      // rows rg*8..+8
    int hg = tid & 15;      // d = hg*4..+4
    float acc[8][4] = {};
    float l[8] = {};

    const float* kfbase = kf + (size_t)bh * SS * 8;
    const float* vbase = V + (size_t)b * SS * HH + h * HDD;
    int vrow = tid >> 2, vc = (tid & 3) * 16;

    for (int t0 = 0; t0 < SS; t0 += 64) {
        __syncthreads();
        if (tid < 128)
            ((float4*)&kfs[0][0])[tid] = ((const float4*)(kfbase + (size_t)t0 * 8))[tid];
        const float* vsrc = vbase + (size_t)(t0 + vrow) * HH + vc;
        float4 v0 = *(const float4*)(vsrc + 0);
        float4 v1 = *(const float4*)(vsrc + 4);
        float4 v2 = *(const float4*)(vsrc + 8);
        float4 v3 = *(const float4*)(vsrc + 12);
        *(float4*)&Vs[vrow][vc + 0]  = v0;
        *(float4*)&Vs[vrow][vc + 4]  = v1;
        *(float4*)&Vs[vrow][vc + 8]  = v2;
        *(float4*)&Vs[vrow][vc + 12] = v3;
        __syncthreads();

        #pragma unroll 4
        for (int i = 0; i < 32; i++) {
            int t = thalf + i;
            float4 klo = *(float4*)&kfs[t][0];
            float4 khi = *(float4*)&kfs[t][4];
            float sc = qlo.x * klo.x + qlo.y * klo.y + qlo.z * klo.z + qlo.w * klo.w
                     + qhi.x * khi.x + qhi.y * khi.y + qhi.z * khi.z + qhi.w * khi.w;
            ps[t][srow] = __expf(sc);
        }
        __syncthreads();

        #pragma unroll 4
        for (int t = 0; t < 64; t++) {
            float4 v = *(float4*)&Vs[t][hg * 4];
            float4 pa = *(float4*)&ps[t][rg * 8];
            float4 pb = *(float4*)&ps[t][rg * 8 + 4];
            float pr[8] = { pa.x, pa.y, pa.z, pa.w, pb.x, pb.y, pb.z, pb.w };
            #pragma unroll
            for (int r = 0; r < 8; r++) {
                acc[r][0] += pr[r] * v.x;
                acc[r][1] += pr[r] * v.y;
                acc[r][2] += pr[r] * v.z;
                acc[r][3] += pr[r] * v.w;
                l[r] += pr[r];
            }
        }
    }

    #pragma unroll
    for (int r = 0; r < 8; r++) {
        int sg = s0 + rg * 8 + r;
        float inv = 1.f / l[r];
        float4 o4 = { acc[r][0] * inv, acc[r][1] * inv, acc[r][2] * inv, acc[r][3] * inv };
        *(float4*)(O + ((size_t)(b * SS + sg)) * HH + h * HDD + hg * 4) = o4;
    }
}

extern "C" void kernel_launch(void* const* d_in, const int* in_sizes, int n_in,
                              void* d_out, int out_size, void* d_ws, size_t ws_size,
                              hipStream_t stream)
{
    // setup_inputs dict order: x, Wq, Wk, Wv, Wo, bq, bk, bv, bo
    const float* x  = (const float*)d_in[0];
    const float* Wq = (const float*)d_in[1];
    const float* Wk = (const float*)d_in[2];
    const float* Wv = (const float*)d_in[3];
    const float* Wo = (const float*)d_in[4];
    const float* bq = (const float*)d_in[5];
    const float* bk = (const float*)d_in[6];
    const float* bv = (const float*)d_in[7];
    const float* bo = (const float*)d_in[8];

    float* qf   = (float*)d_ws;                     // 2*16*2048*8 = 524288 floats
    float* kf   = qf + 524288;                      // 524288 floats
    float* Vws  = kf + 524288;                      // 2*2048*1024 = 4194304 floats
    float* attn = Vws + 4194304;                    // 4194304 floats

    qk_feat_kernel<<<4096, 256, 0, stream>>>(x, Wq, bq, Wk, bk, qf, kf);
    gemm_xt_kernel<<<dim3(8, 32), 256, 0, stream>>>(x, Wv, bv, Vws);
    attn_kernel<<<dim3(16, 32), 256, 0, stream>>>(qf, kf, Vws, attn);
    gemm_xt_kernel<<<dim3(8, 32), 256, 0, stream>>>(attn, Wo, bo, (float*)d_out);
}

// Round 2
// 416.060 us; speedup vs baseline: 1.8355x; 1.8355x over previous
//
#include <hip/hip_runtime.h>
#include <hip/hip_bf16.h>

#define SS 2048
#define HH 1024
#define NHH 16
#define HDD 64

using f32x4  = __attribute__((ext_vector_type(4))) float;
using bf16x8 = __attribute__((ext_vector_type(8))) short;

__device__ __forceinline__ unsigned short f2bf(float f) {
    unsigned u = __builtin_bit_cast(unsigned, f);
    unsigned r = u + 0x7FFFu + ((u >> 16) & 1u);
    return (unsigned short)(r >> 16);
}

__device__ __forceinline__ void tetra(float t, float* c) {
    float a = 1.f / (1.f + __expf(-t));
    float na = 1.f - a;
    float nei = 1.f - (a + na);
    nei = fminf(fmaxf(nei, 0.f), 1.f);
    c[0] = a; c[1] = na; c[2] = a * na; c[3] = nei;
}

// ---------------- cvt: fp32 -> bf16 for x, Wv, Wo ----------------
__global__ __launch_bounds__(256) void cvt_kernel(
    const float* __restrict__ x, const float* __restrict__ Wv, const float* __restrict__ Wo,
    unsigned short* __restrict__ xb, unsigned short* __restrict__ Wvb, unsigned short* __restrict__ Wob)
{
    size_t gid = (size_t)blockIdx.x * 256 + threadIdx.x;
    size_t base = gid * 8;
    if (base < 4194304) {
        float4 a = *(const float4*)(x + base);
        float4 b = *(const float4*)(x + base + 4);
        uint4 pk;
        pk.x = f2bf(a.x) | ((unsigned)f2bf(a.y) << 16);
        pk.y = f2bf(a.z) | ((unsigned)f2bf(a.w) << 16);
        pk.z = f2bf(b.x) | ((unsigned)f2bf(b.y) << 16);
        pk.w = f2bf(b.z) | ((unsigned)f2bf(b.w) << 16);
        *(uint4*)(xb + base) = pk;
    }
    if (base < 1048576) {
        float4 a = *(const float4*)(Wv + base);
        float4 b = *(const float4*)(Wv + base + 4);
        uint4 pk;
        pk.x = f2bf(a.x) | ((unsigned)f2bf(a.y) << 16);
        pk.y = f2bf(a.z) | ((unsigned)f2bf(a.w) << 16);
        pk.z = f2bf(b.x) | ((unsigned)f2bf(b.y) << 16);
        pk.w = f2bf(b.z) | ((unsigned)f2bf(b.w) << 16);
        *(uint4*)(Wvb + base) = pk;
        a = *(const float4*)(Wo + base);
        b = *(const float4*)(Wo + base + 4);
        pk.x = f2bf(a.x) | ((unsigned)f2bf(a.y) << 16);
        pk.y = f2bf(a.z) | ((unsigned)f2bf(a.w) << 16);
        pk.z = f2bf(b.x) | ((unsigned)f2bf(b.y) << 16);
        pk.w = f2bf(b.z) | ((unsigned)f2bf(b.w) << 16);
        *(uint4*)(Wob + base) = pk;
    }
}

// ---------------- qk_feat (unchanged, fp32) ----------------
__global__ __launch_bounds__(256) void qk_feat_kernel(
    const float* __restrict__ x,
    const float* __restrict__ Wq, const float* __restrict__ bq,
    const float* __restrict__ Wk, const float* __restrict__ bk,
    float* __restrict__ qf, float* __restrict__ kf)
{
    __shared__ float xs[HH];
    __shared__ float part[64][4];
    __shared__ float yv[64];
    int tid = threadIdx.x;
    int m = blockIdx.x;
    int b = m >> 11, s = m & 2047;

    ((float4*)xs)[tid] = ((const float4*)(x + (size_t)m * HH))[tid];
    __syncthreads();

    int o = tid >> 2, p = tid & 3;
    int oo = o & 31;
    int h = oo >> 1, hd = (oo & 1) * 2;
    int j = h * HDD + hd;
    const float* W; float bias;
    if (o < 32) { W = Wq; bias = bq[j]; } else { W = Wk; bias = bk[j]; }

    const float4* wr = (const float4*)(W + (size_t)j * HH + p * 256);
    const float4* xr = (const float4*)(xs + p * 256);
    float sum = (p == 0) ? bias : 0.f;
    #pragma unroll 8
    for (int i = 0; i < 64; i++) {
        float4 w4 = wr[i], x4 = xr[i];
        sum += w4.x * x4.x + w4.y * x4.y + w4.z * x4.z + w4.w * x4.w;
    }
    part[o][p] = sum;
    __syncthreads();
    if (tid < 64) yv[tid] = part[tid][0] + part[tid][1] + part[tid][2] + part[tid][3];
    __syncthreads();

    if (tid < 16) {
        int hh = tid;
        float qa[4], qb[4], ka[4], kb[4];
        tetra(yv[2 * hh], qa);
        tetra(yv[2 * hh + 1], qb);
        tetra(yv[32 + 2 * hh], ka);
        tetra(yv[32 + 2 * hh + 1], kb);
        size_t base = ((size_t)(b * NHH + hh) * SS + s) * 8;
        const float inv8 = 0.125f;
        #pragma unroll
        for (int c = 0; c < 4; c++) {
            qf[base + c]     = qa[c] * inv8;
            qf[base + 4 + c] = qb[c] * 0.1f;
            kf[base + c]     = ka[c];
            kf[base + 4 + c] = kb[c];
        }
    }
}

// ---------------- bf16 MFMA GEMM: C[m][n] = sum_k A[m][k]*B[n][k] + bias[n] ----------------
// M=4096 (grid.y*128), N=1024 (grid.x*128), K=1024. 4 waves, each 64x64. BK=32.
template<int OUT_BF16>
__global__ __launch_bounds__(256) void gemm_mfma(
    const unsigned short* __restrict__ A, const unsigned short* __restrict__ Bw,
    const float* __restrict__ bias, void* __restrict__ Cout)
{
    __shared__ unsigned short As[128][40];   // rows padded 32->40 shorts (80B, 16B-aligned)
    __shared__ unsigned short Bs[128][40];
    int tid = threadIdx.x;
    int wave = tid >> 6, lane = tid & 63;
    int l15 = lane & 15, l16 = lane >> 4;
    int wm = wave >> 1, wn = wave & 1;
    int m0 = blockIdx.y * 128, n0 = blockIdx.x * 128;

    int lrow = tid >> 1;
    int lhalf = (tid & 1) * 16;
    const unsigned short* Ap = A + (size_t)(m0 + lrow) * HH + lhalf;
    const unsigned short* Bp = Bw + (size_t)(n0 + lrow) * HH + lhalf;

    f32x4 acc[4][4] = {};

    for (int k0 = 0; k0 < HH; k0 += 32) {
        uint4 a0 = *(const uint4*)(Ap + k0);
        uint4 a1 = *(const uint4*)(Ap + k0 + 8);
        uint4 b0 = *(const uint4*)(Bp + k0);
        uint4 b1 = *(const uint4*)(Bp + k0 + 8);
        __syncthreads();
        *(uint4*)&As[lrow][lhalf]     = a0;
        *(uint4*)&As[lrow][lhalf + 8] = a1;
        *(uint4*)&Bs[lrow][lhalf]     = b0;
        *(uint4*)&Bs[lrow][lhalf + 8] = b1;
        __syncthreads();

        bf16x8 af[4], bf[4];
        #pragma unroll
        for (int mi = 0; mi < 4; mi++)
            af[mi] = *(const bf16x8*)&As[wm * 64 + mi * 16 + l15][l16 * 8];
        #pragma unroll
        for (int ni = 0; ni < 4; ni++)
            bf[ni] = *(const bf16x8*)&Bs[wn * 64 + ni * 16 + l15][l16 * 8];
        #pragma unroll
        for (int mi = 0; mi < 4; mi++)
            #pragma unroll
            for (int ni = 0; ni < 4; ni++)
                acc[mi][ni] = __builtin_amdgcn_mfma_f32_16x16x32_bf16(af[mi], bf[ni], acc[mi][ni], 0, 0, 0);
    }

    float bv[4];
    #pragma unroll
    for (int ni = 0; ni < 4; ni++)
        bv[ni] = bias[n0 + wn * 64 + ni * 16 + l15];

    #pragma unroll
    for (int mi = 0; mi < 4; mi++) {
        #pragma unroll
        for (int ni = 0; ni < 4; ni++) {
            int n = n0 + wn * 64 + ni * 16 + l15;
            #pragma unroll
            for (int r = 0; r < 4; r++) {
                int m = m0 + wm * 64 + mi * 16 + l16 * 4 + r;
                float v = acc[mi][ni][r] + bv[ni];
                if (OUT_BF16)
                    ((unsigned short*)Cout)[(size_t)m * HH + n] = f2bf(v);
                else
                    ((float*)Cout)[(size_t)m * HH + n] = v;
            }
        }
    }
}

// ---------------- transpose V: Vb[b*S+t][h*64+d] -> Vt[(bh*64+d)*S + t] ----------------
__global__ __launch_bounds__(256) void transpose_v(
    const unsigned short* __restrict__ Vb, unsigned short* __restrict__ Vt)
{
    __shared__ unsigned short ts[64][72];
    int tid = threadIdx.x;
    int bh = blockIdx.y, b = bh >> 4, h = bh & 15;
    int t0 = blockIdx.x * 64;

    int tr = tid >> 2, dseg = (tid & 3) * 16;
    const unsigned short* src = Vb + (size_t)(b * SS + t0 + tr) * HH + h * HDD + dseg;
    uint4 a0 = *(const uint4*)src;
    uint4 a1 = *(const uint4*)(src + 8);
    *(uint4*)&ts[tr][dseg]     = a0;
    *(uint4*)&ts[tr][dseg + 8] = a1;
    __syncthreads();

    int d = tid >> 2, tseg = (tid & 3) * 16;
    unsigned short vals[16];
    #pragma unroll
    for (int j = 0; j < 16; j++) vals[j] = ts[tseg + j][d];
    uint4 pk0, pk1;
    pk0.x = vals[0] | ((unsigned)vals[1] << 16);
    pk0.y = vals[2] | ((unsigned)vals[3] << 16);
    pk0.z = vals[4] | ((unsigned)vals[5] << 16);
    pk0.w = vals[6] | ((unsigned)vals[7] << 16);
    pk1.x = vals[8] | ((unsigned)vals[9] << 16);
    pk1.y = vals[10] | ((unsigned)vals[11] << 16);
    pk1.z = vals[12] | ((unsigned)vals[13] << 16);
    pk1.w = vals[14] | ((unsigned)vals[15] << 16);
    unsigned short* dst = Vt + (size_t)(bh * HDD + d) * SS + t0 + tseg;
    *(uint4*)dst = pk0;
    *(uint4*)(dst + 8) = pk1;
}

// ---------------- MFMA flash attention ----------------
// Block: one (b,h), 64 q rows. Tiles of 64 t. Scores in fp32 VALU, PV via MFMA.
__global__ __launch_bounds__(256) void attn_mfma(
    const float* __restrict__ qf, const float* __restrict__ kf,
    const unsigned short* __restrict__ Vt, unsigned short* __restrict__ attnb)
{
    __shared__ unsigned short ps[64][72];   // P[q][t] bf16, stride 144B
    __shared__ unsigned short vt[64][72];   // V^T[d][t] bf16
    __shared__ float kfs[64][8];
    __shared__ float lpart[64][4];
    __shared__ float lfin[64];

    int tid = threadIdx.x;
    int bh = blockIdx.y, b = bh >> 4, h = bh & 15;
    int s0 = blockIdx.x * 64;

    // score mapping: thread -> (q = sq, 16 t's)
    int sq = tid >> 2, tseg = (tid & 3) * 16;
    const float* qrow = qf + ((size_t)bh * SS + s0 + sq) * 8;
    float4 qlo = *(const float4*)qrow;
    float4 qhi = *(const float4*)(qrow + 4);
    float lsum = 0.f;

    // staging mapping
    int vd = tid >> 2, vseg = (tid & 3) * 16;
    const unsigned short* vbase = Vt + ((size_t)bh * HDD + vd) * SS + vseg;
    const float* kfbase = kf + (size_t)bh * SS * 8;

    // mfma mapping
    int wave = tid >> 6, lane = tid & 63;
    int l15 = lane & 15, l16 = lane >> 4;
    f32x4 acc[4] = {};

    for (int t0 = 0; t0 < SS; t0 += 64) {
        __syncthreads();
        if (tid < 128)
            ((float4*)&kfs[0][0])[tid] = ((const float4*)(kfbase + (size_t)t0 * 8))[tid];
        uint4 v0 = *(const uint4*)(vbase + t0);
        uint4 v1 = *(const uint4*)(vbase + t0 + 8);
        *(uint4*)&vt[vd][vseg]     = v0;
        *(uint4*)&vt[vd][vseg + 8] = v1;
        __syncthreads();

        // scores + exp -> bf16 P
        unsigned short pb[16];
        #pragma unroll
        for (int j = 0; j < 16; j++) {
            float4 klo = *(const float4*)&kfs[tseg + j][0];
            float4 khi = *(const float4*)&kfs[tseg + j][4];
            float sc = qlo.x * klo.x + qlo.y * klo.y + qlo.z * klo.z + qlo.w * klo.w
                     + qhi.x * khi.x + qhi.y * khi.y + qhi.z * khi.z + qhi.w * khi.w;
            float pv = __expf(sc);
            lsum += pv;
            pb[j] = f2bf(pv);
        }
        uint4 pk0, pk1;
        pk0.x = pb[0] | ((unsigned)pb[1] << 16);
        pk0.y = pb[2] | ((unsigned)pb[3] << 16);
        pk0.z = pb[4] | ((unsigned)pb[5] << 16);
        pk0.w = pb[6] | ((unsigned)pb[7] << 16);
        pk1.x = pb[8] | ((unsigned)pb[9] << 16);
        pk1.y = pb[10] | ((unsigned)pb[11] << 16);
        pk1.z = pb[12] | ((unsigned)pb[13] << 16);
        pk1.w = pb[14] | ((unsigned)pb[15] << 16);
        *(uint4*)&ps[sq][tseg]     = pk0;
        *(uint4*)&ps[sq][tseg + 8] = pk1;
        __syncthreads();

        // PV: wave handles q rows wave*16..+15, all 64 d
        #pragma unroll
        for (int kk = 0; kk < 64; kk += 32) {
            bf16x8 a = *(const bf16x8*)&ps[wave * 16 + l15][kk + l16 * 8];
            #pragma unroll
            for (int db = 0; db < 4; db++) {
                bf16x8 bfr = *(const bf16x8*)&vt[db * 16 + l15][kk + l16 * 8];
                acc[db] = __builtin_amdgcn_mfma_f32_16x16x32_bf16(a, bfr, acc[db], 0, 0, 0);
            }
        }
    }

    lpart[sq][tid & 3] = lsum;
    __syncthreads();
    if (tid < 64)
        lfin[tid] = lpart[tid][0] + lpart[tid][1] + lpart[tid][2] + lpart[tid][3];
    __syncthreads();

    #pragma unroll
    for (int r = 0; r < 4; r++) {
        int q = wave * 16 + l16 * 4 + r;
        float inv = 1.f / lfin[q];
        size_t orow = (size_t)(b * SS + s0 + q) * HH + h * HDD;
        #pragma unroll
        for (int db = 0; db < 4; db++)
            attnb[orow + db * 16 + l15] = f2bf(acc[db][r] * inv);
    }
}

extern "C" void kernel_launch(void* const* d_in, const int* in_sizes, int n_in,
                              void* d_out, int out_size, void* d_ws, size_t ws_size,
                              hipStream_t stream)
{
    const float* x  = (const float*)d_in[0];
    const float* Wq = (const float*)d_in[1];
    const float* Wk = (const float*)d_in[2];
    const float* Wv = (const float*)d_in[3];
    const float* Wo = (const float*)d_in[4];
    const float* bq = (const float*)d_in[5];
    const float* bk = (const float*)d_in[6];
    const float* bv = (const float*)d_in[7];
    const float* bo = (const float*)d_in[8];

    // workspace layout (32 MB total)
    float* qf = (float*)d_ws;                          // 524288 f
    float* kf = qf + 524288;                           // 524288 f
    unsigned short* xb    = (unsigned short*)(kf + 524288);  // 4194304 us (aliased w/ attnb)
    unsigned short* attnb = xb;                              // alias: xb dead after V-GEMM
    unsigned short* Wvb   = xb + 4194304;              // 1048576 us
    unsigned short* Wob   = Wvb + 1048576;             // 1048576 us
    unsigned short* Vb    = Wob + 1048576;             // 4194304 us
    unsigned short* Vt    = Vb + 4194304;              // 4194304 us

    cvt_kernel<<<2048, 256, 0, stream>>>(x, Wv, Wo, xb, Wvb, Wob);
    qk_feat_kernel<<<4096, 256, 0, stream>>>(x, Wq, bq, Wk, bk, qf, kf);
    gemm_mfma<1><<<dim3(8, 32), 256, 0, stream>>>(xb, Wvb, bv, Vb);
    transpose_v<<<dim3(32, 32), 256, 0, stream>>>(Vb, Vt);
    attn_mfma<<<dim3(32, 32), 256, 0, stream>>>(qf, kf, Vt, attnb);
    gemm_mfma<0><<<dim3(8, 32), 256, 0, stream>>>(attnb, Wob, bo, (float*)d_out);
}

// Round 3
// 327.350 us; speedup vs baseline: 2.3329x; 1.2710x over previous
//
#include <hip/hip_runtime.h>
#include <hip/hip_bf16.h>

#define SS 2048
#define HH 1024
#define NHH 16
#define HDD 64

using f32x4  = __attribute__((ext_vector_type(4))) float;
using bf16x8 = __attribute__((ext_vector_type(8))) short;

__device__ __forceinline__ unsigned short f2bf(float f) {
    unsigned u = __builtin_bit_cast(unsigned, f);
    unsigned r = u + 0x7FFFu + ((u >> 16) & 1u);
    return (unsigned short)(r >> 16);
}

__device__ __forceinline__ void tetra(float t, float* c) {
    float a = 1.f / (1.f + __expf(-t));
    float na = 1.f - a;
    float nei = 1.f - (a + na);
    nei = fminf(fmaxf(nei, 0.f), 1.f);
    c[0] = a; c[1] = na; c[2] = a * na; c[3] = nei;
}

// ---------------- cvt: fp32 -> bf16 for x, Wv, Wo ----------------
__global__ __launch_bounds__(256) void cvt_kernel(
    const float* __restrict__ x, const float* __restrict__ Wv, const float* __restrict__ Wo,
    unsigned short* __restrict__ xb, unsigned short* __restrict__ Wvb, unsigned short* __restrict__ Wob)
{
    size_t gid = (size_t)blockIdx.x * 256 + threadIdx.x;
    size_t base = gid * 8;
    if (base < 4194304) {
        float4 a = *(const float4*)(x + base);
        float4 b = *(const float4*)(x + base + 4);
        uint4 pk;
        pk.x = f2bf(a.x) | ((unsigned)f2bf(a.y) << 16);
        pk.y = f2bf(a.z) | ((unsigned)f2bf(a.w) << 16);
        pk.z = f2bf(b.x) | ((unsigned)f2bf(b.y) << 16);
        pk.w = f2bf(b.z) | ((unsigned)f2bf(b.w) << 16);
        *(uint4*)(xb + base) = pk;
    }
    if (base < 1048576) {
        float4 a = *(const float4*)(Wv + base);
        float4 b = *(const float4*)(Wv + base + 4);
        uint4 pk;
        pk.x = f2bf(a.x) | ((unsigned)f2bf(a.y) << 16);
        pk.y = f2bf(a.z) | ((unsigned)f2bf(a.w) << 16);
        pk.z = f2bf(b.x) | ((unsigned)f2bf(b.y) << 16);
        pk.w = f2bf(b.z) | ((unsigned)f2bf(b.w) << 16);
        *(uint4*)(Wvb + base) = pk;
        a = *(const float4*)(Wo + base);
        b = *(const float4*)(Wo + base + 4);
        pk.x = f2bf(a.x) | ((unsigned)f2bf(a.y) << 16);
        pk.y = f2bf(a.z) | ((unsigned)f2bf(a.w) << 16);
        pk.z = f2bf(b.x) | ((unsigned)f2bf(b.y) << 16);
        pk.w = f2bf(b.z) | ((unsigned)f2bf(b.w) << 16);
        *(uint4*)(Wob + base) = pk;
    }
}

// ---------------- qk_feat: fp32 compute, bf16 packed features out ----------------
__global__ __launch_bounds__(256) void qk_feat_kernel(
    const float* __restrict__ x,
    const float* __restrict__ Wq, const float* __restrict__ bq,
    const float* __restrict__ Wk, const float* __restrict__ bk,
    unsigned short* __restrict__ qfb, unsigned short* __restrict__ kfb)
{
    __shared__ float xs[HH];
    __shared__ float part[64][4];
    __shared__ float yv[64];
    int tid = threadIdx.x;
    int m = blockIdx.x;
    int b = m >> 11, s = m & 2047;

    ((float4*)xs)[tid] = ((const float4*)(x + (size_t)m * HH))[tid];
    __syncthreads();

    int o = tid >> 2, p = tid & 3;
    int oo = o & 31;
    int h = oo >> 1, hd = (oo & 1) * 2;
    int j = h * HDD + hd;
    const float* W; float bias;
    if (o < 32) { W = Wq; bias = bq[j]; } else { W = Wk; bias = bk[j]; }

    const float4* wr = (const float4*)(W + (size_t)j * HH + p * 256);
    const float4* xr = (const float4*)(xs + p * 256);
    float sum = (p == 0) ? bias : 0.f;
    #pragma unroll 8
    for (int i = 0; i < 64; i++) {
        float4 w4 = wr[i], x4 = xr[i];
        sum += w4.x * x4.x + w4.y * x4.y + w4.z * x4.z + w4.w * x4.w;
    }
    part[o][p] = sum;
    __syncthreads();
    if (tid < 64) yv[tid] = part[tid][0] + part[tid][1] + part[tid][2] + part[tid][3];
    __syncthreads();

    if (tid < 16) {
        int hh = tid;
        float qa[4], qb2[4], ka[4], kb2[4];
        tetra(yv[2 * hh], qa);
        tetra(yv[2 * hh + 1], qb2);
        tetra(yv[32 + 2 * hh], ka);
        tetra(yv[32 + 2 * hh + 1], kb2);
        size_t base = ((size_t)(b * NHH + hh) * SS + s) * 8;
        unsigned short q8[8], k8[8];
        #pragma unroll
        for (int c = 0; c < 4; c++) {
            q8[c]     = f2bf(qa[c] * 0.125f);
            q8[4 + c] = f2bf(qb2[c] * 0.1f);
            k8[c]     = f2bf(ka[c]);
            k8[4 + c] = f2bf(kb2[c]);
        }
        uint4 qp, kp;
        qp.x = q8[0] | ((unsigned)q8[1] << 16); qp.y = q8[2] | ((unsigned)q8[3] << 16);
        qp.z = q8[4] | ((unsigned)q8[5] << 16); qp.w = q8[6] | ((unsigned)q8[7] << 16);
        kp.x = k8[0] | ((unsigned)k8[1] << 16); kp.y = k8[2] | ((unsigned)k8[3] << 16);
        kp.z = k8[4] | ((unsigned)k8[5] << 16); kp.w = k8[6] | ((unsigned)k8[7] << 16);
        *(uint4*)(qfb + base) = qp;
        *(uint4*)(kfb + base) = kp;
    }
}

// ---------------- bf16 MFMA GEMM: C[m][n] = sum_k A[m][k]*B[n][k] + bias[n] ----------------
// 128m x 64n tile, BK=64, 4 waves each 64m x 32n. grid (N/64, M/128) = (16,32) = 512 blocks.
template<int OUT_BF16>
__global__ __launch_bounds__(256) void gemm_mfma(
    const unsigned short* __restrict__ A, const unsigned short* __restrict__ Bw,
    const float* __restrict__ bias, void* __restrict__ Cout)
{
    __shared__ unsigned short As[128][72];
    __shared__ unsigned short Bs[64][72];
    int tid = threadIdx.x;
    int wave = tid >> 6, lane = tid & 63;
    int l15 = lane & 15, l16 = lane >> 4;
    int wm = wave >> 1, wn = wave & 1;
    int m0 = blockIdx.y * 128, n0 = blockIdx.x * 64;

    int ar = tid >> 1, aseg = (tid & 1) * 32;
    int br = tid >> 2, bseg = (tid & 3) * 16;
    const unsigned short* Ap = A + (size_t)(m0 + ar) * HH + aseg;
    const unsigned short* Bp = Bw + (size_t)(n0 + br) * HH + bseg;

    f32x4 acc[4][2] = {};

    for (int k0 = 0; k0 < HH; k0 += 64) {
        uint4 a0 = *(const uint4*)(Ap + k0);
        uint4 a1 = *(const uint4*)(Ap + k0 + 8);
        uint4 a2 = *(const uint4*)(Ap + k0 + 16);
        uint4 a3 = *(const uint4*)(Ap + k0 + 24);
        uint4 b0 = *(const uint4*)(Bp + k0);
        uint4 b1 = *(const uint4*)(Bp + k0 + 8);
        __syncthreads();
        *(uint4*)&As[ar][aseg]      = a0;
        *(uint4*)&As[ar][aseg + 8]  = a1;
        *(uint4*)&As[ar][aseg + 16] = a2;
        *(uint4*)&As[ar][aseg + 24] = a3;
        *(uint4*)&Bs[br][bseg]      = b0;
        *(uint4*)&Bs[br][bseg + 8]  = b1;
        __syncthreads();

        #pragma unroll
        for (int kk = 0; kk < 64; kk += 32) {
            bf16x8 af[4], bfr[2];
            #pragma unroll
            for (int mi = 0; mi < 4; mi++)
                af[mi] = *(const bf16x8*)&As[wm * 64 + mi * 16 + l15][kk + l16 * 8];
            #pragma unroll
            for (int ni = 0; ni < 2; ni++)
                bfr[ni] = *(const bf16x8*)&Bs[wn * 32 + ni * 16 + l15][kk + l16 * 8];
            #pragma unroll
            for (int mi = 0; mi < 4; mi++)
                #pragma unroll
                for (int ni = 0; ni < 2; ni++)
                    acc[mi][ni] = __builtin_amdgcn_mfma_f32_16x16x32_bf16(af[mi], bfr[ni], acc[mi][ni], 0, 0, 0);
        }
    }

    float bv[2];
    #pragma unroll
    for (int ni = 0; ni < 2; ni++)
        bv[ni] = bias[n0 + wn * 32 + ni * 16 + l15];

    #pragma unroll
    for (int mi = 0; mi < 4; mi++) {
        #pragma unroll
        for (int ni = 0; ni < 2; ni++) {
            int n = n0 + wn * 32 + ni * 16 + l15;
            #pragma unroll
            for (int r = 0; r < 4; r++) {
                int m = m0 + wm * 64 + mi * 16 + l16 * 4 + r;
                float v = acc[mi][ni][r] + bv[ni];
                if (OUT_BF16)
                    ((unsigned short*)Cout)[(size_t)m * HH + n] = f2bf(v);
                else
                    ((float*)Cout)[(size_t)m * HH + n] = v;
            }
        }
    }
}

// ---------------- transpose V: Vb[b*S+t][h*64+d] -> Vt[(bh*64+d)*S + t] ----------------
__global__ __launch_bounds__(256) void transpose_v(
    const unsigned short* __restrict__ Vb, unsigned short* __restrict__ Vt)
{
    __shared__ unsigned short ts[64][72];
    int tid = threadIdx.x;
    int bh = blockIdx.y, b = bh >> 4, h = bh & 15;
    int t0 = blockIdx.x * 64;

    int tr = tid >> 2, dseg = (tid & 3) * 16;
    const unsigned short* src = Vb + (size_t)(b * SS + t0 + tr) * HH + h * HDD + dseg;
    uint4 a0 = *(const uint4*)src;
    uint4 a1 = *(const uint4*)(src + 8);
    *(uint4*)&ts[tr][dseg]     = a0;
    *(uint4*)&ts[tr][dseg + 8] = a1;
    __syncthreads();

    int d = tid >> 2, tseg = (tid & 3) * 16;
    unsigned short vals[16];
    #pragma unroll
    for (int j = 0; j < 16; j++) vals[j] = ts[tseg + j][d];
    uint4 pk0, pk1;
    pk0.x = vals[0] | ((unsigned)vals[1] << 16);
    pk0.y = vals[2] | ((unsigned)vals[3] << 16);
    pk0.z = vals[4] | ((unsigned)vals[5] << 16);
    pk0.w = vals[6] | ((unsigned)vals[7] << 16);
    pk1.x = vals[8] | ((unsigned)vals[9] << 16);
    pk1.y = vals[10] | ((unsigned)vals[11] << 16);
    pk1.z = vals[12] | ((unsigned)vals[13] << 16);
    pk1.w = vals[14] | ((unsigned)vals[15] << 16);
    unsigned short* dst = Vt + (size_t)(bh * HDD + d) * SS + t0 + tseg;
    *(uint4*)dst = pk0;
    *(uint4*)(dst + 8) = pk1;
}

// ---------------- MFMA flash attention, scores AND PV on matrix pipe ----------------
// Block: one (b,h), 128 q (4 waves x 32 q). Tiles of 64 t.
// Score MFMA: D[t][q] = Kf[t][f] * Qf[q][f] (f in k=0..7, rest zero via zeroed Qf frag).
// PV MFMA:    D[q][d] = P[q][t] * Vt[d][t].
__global__ __launch_bounds__(256) void attn_mfma(
    const unsigned short* __restrict__ qfb, const unsigned short* __restrict__ kfb,
    const unsigned short* __restrict__ Vt, unsigned short* __restrict__ attnb)
{
    __shared__ unsigned short vt[64][72];       // V^T tile [d][t]
    __shared__ unsigned short ps[4][32][72];    // per-wave P [q][t]

    int tid = threadIdx.x;
    int wave = tid >> 6, lane = tid & 63;
    int l15 = lane & 15, l16 = lane >> 4;
    int bh = blockIdx.y, b = bh >> 4, h = bh & 15;
    int s0 = blockIdx.x * 128 + wave * 32;      // this wave's q base

    // Qf B-frags: only k=0..7 (l16==0) nonzero
    bf16x8 bfq0 = {0,0,0,0,0,0,0,0};
    bf16x8 bfq1 = {0,0,0,0,0,0,0,0};
    if (l16 == 0) {
        bfq0 = *(const bf16x8*)(qfb + ((size_t)bh * SS + s0 + l15) * 8);
        bfq1 = *(const bf16x8*)(qfb + ((size_t)bh * SS + s0 + 16 + l15) * 8);
    }

    const unsigned short* kfB = kfb + (size_t)bh * SS * 8;
    const unsigned short* vtB = Vt + (size_t)bh * HDD * SS;

    int vd = tid >> 2, vseg = (tid & 3) * 16;   // vt staging: row d, 16-short seg

    f32x4 acc[2][4] = {};                        // [mq][nd]
    float lsum[2] = {0.f, 0.f};

    for (int t0 = 0; t0 < SS; t0 += 64) {
        __syncthreads();
        {
            const unsigned short* src = vtB + (size_t)vd * SS + t0 + vseg;
            uint4 v0 = *(const uint4*)src;
            uint4 v1 = *(const uint4*)(src + 8);
            *(uint4*)&vt[vd][vseg]     = v0;
            *(uint4*)&vt[vd][vseg + 8] = v1;
        }
        __syncthreads();

        // scores: 4 t-blocks x 2 q-groups
        #pragma unroll
        for (int tb = 0; tb < 4; tb++) {
            bf16x8 af = *(const bf16x8*)(kfB + (size_t)(t0 + tb * 16 + l15) * 8);
            #pragma unroll
            for (int qg = 0; qg < 2; qg++) {
                f32x4 sc = {};
                sc = __builtin_amdgcn_mfma_f32_16x16x32_bf16(af, qg ? bfq1 : bfq0, sc, 0, 0, 0);
                float p0 = __expf(sc[0]);
                float p1 = __expf(sc[1]);
                float p2 = __expf(sc[2]);
                float p3 = __expf(sc[3]);
                lsum[qg] += (p0 + p1) + (p2 + p3);
                uint2 pw;
                pw.x = f2bf(p0) | ((unsigned)f2bf(p1) << 16);
                pw.y = f2bf(p2) | ((unsigned)f2bf(p3) << 16);
                // thread holds (q = qg*16+l15, t = tb*16 + l16*4 + 0..3)
                *(uint2*)&ps[wave][qg * 16 + l15][tb * 16 + l16 * 4] = pw;
            }
        }

        // PV: k-chunks of 32 t
        #pragma unroll
        for (int tk = 0; tk < 2; tk++) {
            bf16x8 bv[4];
            #pragma unroll
            for (int nd = 0; nd < 4; nd++)
                bv[nd] = *(const bf16x8*)&vt[nd * 16 + l15][tk * 32 + l16 * 8];
            #pragma unroll
            for (int mq = 0; mq < 2; mq++) {
                bf16x8 ap = *(const bf16x8*)&ps[wave][mq * 16 + l15][tk * 32 + l16 * 8];
                #pragma unroll
                for (int nd = 0; nd < 4; nd++)
                    acc[mq][nd] = __builtin_amdgcn_mfma_f32_16x16x32_bf16(ap, bv[nd], acc[mq][nd], 0, 0, 0);
            }
        }
    }

    // reduce l over the t-partition lanes (same l15, l16 = 0..3)
    #pragma unroll
    for (int qg = 0; qg < 2; qg++) {
        float v = lsum[qg];
        v += __shfl_xor(v, 16, 64);
        v += __shfl_xor(v, 32, 64);
        lsum[qg] = v;   // every lane now holds l for q = qg*16 + l15
    }

    #pragma unroll
    for (int mq = 0; mq < 2; mq++) {
        float linv[4];
        #pragma unroll
        for (int r = 0; r < 4; r++)
            linv[r] = 1.f / __shfl(lsum[mq], l16 * 4 + r, 64);
        #pragma unroll
        for (int r = 0; r < 4; r++) {
            int q = s0 + mq * 16 + l16 * 4 + r;
            size_t row = (size_t)(b * SS + q) * HH + h * HDD;
            #pragma unroll
            for (int nd = 0; nd < 4; nd++)
                attnb[row + nd * 16 + l15] = f2bf(acc[mq][nd][r] * linv[r]);
        }
    }
}

extern "C" void kernel_launch(void* const* d_in, const int* in_sizes, int n_in,
                              void* d_out, int out_size, void* d_ws, size_t ws_size,
                              hipStream_t stream)
{
    const float* x  = (const float*)d_in[0];
    const float* Wq = (const float*)d_in[1];
    const float* Wk = (const float*)d_in[2];
    const float* Wv = (const float*)d_in[3];
    const float* Wo = (const float*)d_in[4];
    const float* bq = (const float*)d_in[5];
    const float* bk = (const float*)d_in[6];
    const float* bv = (const float*)d_in[7];
    const float* bo = (const float*)d_in[8];

    // workspace (30 MB total)
    unsigned short* qfb   = (unsigned short*)d_ws;     // 524288
    unsigned short* kfb   = qfb + 524288;              // 524288
    unsigned short* xb    = kfb + 524288;              // 4194304 (aliased w/ attnb)
    unsigned short* attnb = xb;                        // alias: xb dead after V-GEMM
    unsigned short* Wvb   = xb + 4194304;              // 1048576
    unsigned short* Wob   = Wvb + 1048576;             // 1048576
    unsigned short* Vb    = Wob + 1048576;             // 4194304
    unsigned short* Vt    = Vb + 4194304;              // 4194304

    cvt_kernel<<<2048, 256, 0, stream>>>(x, Wv, Wo, xb, Wvb, Wob);
    qk_feat_kernel<<<4096, 256, 0, stream>>>(x, Wq, bq, Wk, bk, qfb, kfb);
    gemm_mfma<1><<<dim3(16, 32), 256, 0, stream>>>(xb, Wvb, bv, Vb);
    transpose_v<<<dim3(32, 32), 256, 0, stream>>>(Vb, Vt);
    attn_mfma<<<dim3(16, 32), 256, 0, stream>>>(qfb, kfb, Vt, attnb);
    gemm_mfma<0><<<dim3(16, 32), 256, 0, stream>>>(attnb, Wob, bo, (float*)d_out);
}

// Round 6
// 221.455 us; speedup vs baseline: 3.4485x; 1.4782x over previous
//
#include <hip/hip_runtime.h>
#include <hip/hip_bf16.h>

#define SS 2048
#define HH 1024
#define NHH 16
#define HDD 64

using f32x4  = __attribute__((ext_vector_type(4))) float;
using bf16x8 = __attribute__((ext_vector_type(8))) short;

__device__ __forceinline__ unsigned short f2bf(float f) {
    unsigned u = __builtin_bit_cast(unsigned, f);
    unsigned r = u + 0x7FFFu + ((u >> 16) & 1u);
    return (unsigned short)(r >> 16);
}

__device__ __forceinline__ void tetra(float t, float* c) {
    float a = 1.f / (1.f + __expf(-t));
    float na = 1.f - a;
    float nei = 1.f - (a + na);
    nei = fminf(fmaxf(nei, 0.f), 1.f);
    c[0] = a; c[1] = na; c[2] = a * na; c[3] = nei;
}

// ---------------- cvt: fp32 -> bf16 for x, Wv, Wo; blocks >=2048 gather Wsel ----------------
// Wsel row n (n=0..63): h=n>>2, c=n&3: c0->Wq[h*64+0], c1->Wq[h*64+2], c2->Wk[h*64+0], c3->Wk[h*64+2]
__global__ __launch_bounds__(256) void cvt_kernel(
    const float* __restrict__ x, const float* __restrict__ Wv, const float* __restrict__ Wo,
    const float* __restrict__ Wq, const float* __restrict__ Wk,
    const float* __restrict__ bq, const float* __restrict__ bk,
    unsigned short* __restrict__ xb, unsigned short* __restrict__ Wvb, unsigned short* __restrict__ Wob,
    unsigned short* __restrict__ wselb, float* __restrict__ bselws)
{
    if (blockIdx.x >= 2048) {
        int n = blockIdx.x - 2048;
        int h = n >> 2, q = n & 3;
        int rowIdx = h * HDD + ((q & 1) ? 2 : 0);
        const float* src  = (q & 2) ? Wk : Wq;
        const float* bsrc = (q & 2) ? bk : bq;
        int t = threadIdx.x;
        float4 v = *(const float4*)(src + (size_t)rowIdx * HH + t * 4);
        uint2 pk;
        pk.x = f2bf(v.x) | ((unsigned)f2bf(v.y) << 16);
        pk.y = f2bf(v.z) | ((unsigned)f2bf(v.w) << 16);
        *(uint2*)(wselb + (size_t)n * HH + t * 4) = pk;
        if (t == 0) bselws[n] = bsrc[rowIdx];
        return;
    }
    size_t gid = (size_t)blockIdx.x * 256 + threadIdx.x;
    size_t base = gid * 8;
    {
        float4 a = *(const float4*)(x + base);
        float4 b = *(const float4*)(x + base + 4);
        uint4 pk;
        pk.x = f2bf(a.x) | ((unsigned)f2bf(a.y) << 16);
        pk.y = f2bf(a.z) | ((unsigned)f2bf(a.w) << 16);
        pk.z = f2bf(b.x) | ((unsigned)f2bf(b.y) << 16);
        pk.w = f2bf(b.z) | ((unsigned)f2bf(b.w) << 16);
        *(uint4*)(xb + base) = pk;
    }
    if (base < 1048576) {
        float4 a = *(const float4*)(Wv + base);
        float4 b = *(const float4*)(Wv + base + 4);
        uint4 pk;
        pk.x = f2bf(a.x) | ((unsigned)f2bf(a.y) << 16);
        pk.y = f2bf(a.z) | ((unsigned)f2bf(a.w) << 16);
        pk.z = f2bf(b.x) | ((unsigned)f2bf(b.y) << 16);
        pk.w = f2bf(b.z) | ((unsigned)f2bf(b.w) << 16);
        *(uint4*)(Wvb + base) = pk;
        a = *(const float4*)(Wo + base);
        b = *(const float4*)(Wo + base + 4);
        pk.x = f2bf(a.x) | ((unsigned)f2bf(a.y) << 16);
        pk.y = f2bf(a.z) | ((unsigned)f2bf(a.w) << 16);
        pk.z = f2bf(b.x) | ((unsigned)f2bf(b.y) << 16);
        pk.w = f2bf(b.z) | ((unsigned)f2bf(b.w) << 16);
        *(uint4*)(Wob + base) = pk;
    }
}

// ---------------- qk feature GEMM + tetra epilogue ----------------
// Y[m][n] = xb[m][:] . Wsel[n][:] + bsel[n];  m = b*S+s (4096), n = 64.
// Block: 32 m-rows, 4 waves (wave w: n = w*16..w*16+15, all 32 m). BK=64.
__global__ __launch_bounds__(256) void qk_gemm_kernel(
    const unsigned short* __restrict__ xb, const unsigned short* __restrict__ wselb,
    const float* __restrict__ bselws,
    unsigned short* __restrict__ qfb, unsigned short* __restrict__ kfb)
{
    __shared__ unsigned short xs[32][72];
    __shared__ unsigned short ws[64][72];
    __shared__ float ys[32][68];
    int tid = threadIdx.x;
    int wave = tid >> 6, lane = tid & 63;
    int l15 = lane & 15, l16 = lane >> 4;
    int m0 = blockIdx.x * 32;
    int n0w = wave * 16;

    int xr = tid >> 3, xseg = (tid & 7) * 8;    // 8 thr/row x 8 shorts = full 64
    int wr = tid >> 2, wseg = (tid & 3) * 16;   // 4 thr/row x 16 shorts = full 64
    const unsigned short* xp = xb + (size_t)(m0 + xr) * HH + xseg;
    const unsigned short* wp = wselb + (size_t)wr * HH + wseg;

    f32x4 acc[2] = {};

    for (int k0 = 0; k0 < HH; k0 += 64) {
        uint4 xv = *(const uint4*)(xp + k0);
        uint4 wv0 = *(const uint4*)(wp + k0);
        uint4 wv1 = *(const uint4*)(wp + k0 + 8);
        __syncthreads();
        *(uint4*)&xs[xr][xseg] = xv;
        *(uint4*)&ws[wr][wseg]     = wv0;
        *(uint4*)&ws[wr][wseg + 8] = wv1;
        __syncthreads();
        #pragma unroll
        for (int kk = 0; kk < 64; kk += 32) {
            bf16x8 bfr = *(const bf16x8*)&ws[n0w + l15][kk + l16 * 8];
            #pragma unroll
            for (int mi = 0; mi < 2; mi++) {
                bf16x8 af = *(const bf16x8*)&xs[mi * 16 + l15][kk + l16 * 8];
                acc[mi] = __builtin_amdgcn_mfma_f32_16x16x32_bf16(af, bfr, acc[mi], 0, 0, 0);
            }
        }
    }

    float bias = bselws[n0w + l15];
    __syncthreads();
    #pragma unroll
    for (int mi = 0; mi < 2; mi++)
        #pragma unroll
        for (int r = 0; r < 4; r++)
            ys[mi * 16 + l16 * 4 + r][n0w + l15] = acc[mi][r] + bias;
    __syncthreads();

    // repack: lanes 0..31 = consecutive m (coalesced qfb/kfb writes), tid>>5 = h
    #pragma unroll
    for (int pass = 0; pass < 2; pass++) {
        int ml = tid & 31;
        int h = (tid >> 5) + pass * 8;
        float4 y4 = *(const float4*)&ys[ml][h * 4];
        float qa[4], qb2[4], ka[4], kb2[4];
        tetra(y4.x, qa);
        tetra(y4.y, qb2);
        tetra(y4.z, ka);
        tetra(y4.w, kb2);
        int m = m0 + ml, b = m >> 11, s = m & 2047;
        size_t base = ((size_t)(b * NHH + h) * SS + s) * 8;
        unsigned short q8[8], k8[8];
        #pragma unroll
        for (int c = 0; c < 4; c++) {
            q8[c]     = f2bf(qa[c] * 0.125f);
            q8[4 + c] = f2bf(qb2[c] * 0.1f);
            k8[c]     = f2bf(ka[c]);
            k8[4 + c] = f2bf(kb2[c]);
        }
        uint4 qp, kp;
        qp.x = q8[0] | ((unsigned)q8[1] << 16); qp.y = q8[2] | ((unsigned)q8[3] << 16);
        qp.z = q8[4] | ((unsigned)q8[5] << 16); qp.w = q8[6] | ((unsigned)q8[7] << 16);
        kp.x = k8[0] | ((unsigned)k8[1] << 16); kp.y = k8[2] | ((unsigned)k8[3] << 16);
        kp.z = k8[4] | ((unsigned)k8[5] << 16); kp.w = k8[6] | ((unsigned)k8[7] << 16);
        *(uint4*)(qfb + base) = qp;
        *(uint4*)(kfb + base) = kp;
    }
}

// ---------------- bf16 MFMA GEMM: C[m][n] = sum_k A[m][k]*B[n][k] + bias[n] ----------------
// 128m x 64n tile, BK=64, 4 waves each 64m x 32n. grid (N/64, M/128) = (16,32) = 512 blocks.
template<int OUT_BF16>
__global__ __launch_bounds__(256) void gemm_mfma(
    const unsigned short* __restrict__ A, const unsigned short* __restrict__ Bw,
    const float* __restrict__ bias, void* __restrict__ Cout)
{
    __shared__ unsigned short As[128][72];
    __shared__ unsigned short Bs[64][72];
    int tid = threadIdx.x;
    int wave = tid >> 6, lane = tid & 63;
    int l15 = lane & 15, l16 = lane >> 4;
    int wm = wave >> 1, wn = wave & 1;
    int m0 = blockIdx.y * 128, n0 = blockIdx.x * 64;

    int ar = tid >> 1, aseg = (tid & 1) * 32;
    int br = tid >> 2, bseg = (tid & 3) * 16;
    const unsigned short* Ap = A + (size_t)(m0 + ar) * HH + aseg;
    const unsigned short* Bp = Bw + (size_t)(n0 + br) * HH + bseg;

    f32x4 acc[4][2] = {};

    for (int k0 = 0; k0 < HH; k0 += 64) {
        uint4 a0 = *(const uint4*)(Ap + k0);
        uint4 a1 = *(const uint4*)(Ap + k0 + 8);
        uint4 a2 = *(const uint4*)(Ap + k0 + 16);
        uint4 a3 = *(const uint4*)(Ap + k0 + 24);
        uint4 b0 = *(const uint4*)(Bp + k0);
        uint4 b1 = *(const uint4*)(Bp + k0 + 8);
        __syncthreads();
        *(uint4*)&As[ar][aseg]      = a0;
        *(uint4*)&As[ar][aseg + 8]  = a1;
        *(uint4*)&As[ar][aseg + 16] = a2;
        *(uint4*)&As[ar][aseg + 24] = a3;
        *(uint4*)&Bs[br][bseg]      = b0;
        *(uint4*)&Bs[br][bseg + 8]  = b1;
        __syncthreads();

        #pragma unroll
        for (int kk = 0; kk < 64; kk += 32) {
            bf16x8 af[4], bfr[2];
            #pragma unroll
            for (int mi = 0; mi < 4; mi++)
                af[mi] = *(const bf16x8*)&As[wm * 64 + mi * 16 + l15][kk + l16 * 8];
            #pragma unroll
            for (int ni = 0; ni < 2; ni++)
                bfr[ni] = *(const bf16x8*)&Bs[wn * 32 + ni * 16 + l15][kk + l16 * 8];
            #pragma unroll
            for (int mi = 0; mi < 4; mi++)
                #pragma unroll
                for (int ni = 0; ni < 2; ni++)
                    acc[mi][ni] = __builtin_amdgcn_mfma_f32_16x16x32_bf16(af[mi], bfr[ni], acc[mi][ni], 0, 0, 0);
        }
    }

    float bv[2];
    #pragma unroll
    for (int ni = 0; ni < 2; ni++)
        bv[ni] = bias[n0 + wn * 32 + ni * 16 + l15];

    #pragma unroll
    for (int mi = 0; mi < 4; mi++) {
        #pragma unroll
        for (int ni = 0; ni < 2; ni++) {
            int n = n0 + wn * 32 + ni * 16 + l15;
            #pragma unroll
            for (int r = 0; r < 4; r++) {
                int m = m0 + wm * 64 + mi * 16 + l16 * 4 + r;
                float v = acc[mi][ni][r] + bv[ni];
                if (OUT_BF16)
                    ((unsigned short*)Cout)[(size_t)m * HH + n] = f2bf(v);
                else
                    ((float*)Cout)[(size_t)m * HH + n] = v;
            }
        }
    }
}

// ---------------- transpose V: Vb[b*S+t][h*64+d] -> Vt[(bh*64+d)*S + t] ----------------
__global__ __launch_bounds__(256) void transpose_v(
    const unsigned short* __restrict__ Vb, unsigned short* __restrict__ Vt)
{
    __shared__ unsigned short ts[64][72];
    int tid = threadIdx.x;
    int bh = blockIdx.y, b = bh >> 4, h = bh & 15;
    int t0 = blockIdx.x * 64;

    int tr = tid >> 2, dseg = (tid & 3) * 16;
    const unsigned short* src = Vb + (size_t)(b * SS + t0 + tr) * HH + h * HDD + dseg;
    uint4 a0 = *(const uint4*)src;
    uint4 a1 = *(const uint4*)(src + 8);
    *(uint4*)&ts[tr][dseg]     = a0;
    *(uint4*)&ts[tr][dseg + 8] = a1;
    __syncthreads();

    int d = tid >> 2, tseg = (tid & 3) * 16;
    unsigned short vals[16];
    #pragma unroll
    for (int j = 0; j < 16; j++) vals[j] = ts[tseg + j][d];
    uint4 pk0, pk1;
    pk0.x = vals[0] | ((unsigned)vals[1] << 16);
    pk0.y = vals[2] | ((unsigned)vals[3] << 16);
    pk0.z = vals[4] | ((unsigned)vals[5] << 16);
    pk0.w = vals[6] | ((unsigned)vals[7] << 16);
    pk1.x = vals[8] | ((unsigned)vals[9] << 16);
    pk1.y = vals[10] | ((unsigned)vals[11] << 16);
    pk1.z = vals[12] | ((unsigned)vals[13] << 16);
    pk1.w = vals[14] | ((unsigned)vals[15] << 16);
    unsigned short* dst = Vt + (size_t)(bh * HDD + d) * SS + t0 + tseg;
    *(uint4*)dst = pk0;
    *(uint4*)(dst + 8) = pk1;
}

// ---------------- MFMA flash attention, scores AND PV on matrix pipe ----------------
__global__ __launch_bounds__(256) void attn_mfma(
    const unsigned short* __restrict__ qfb, const unsigned short* __restrict__ kfb,
    const unsigned short* __restrict__ Vt, unsigned short* __restrict__ attnb)
{
    __shared__ unsigned short vt[64][72];       // V^T tile [d][t]
    __shared__ unsigned short ps[4][32][72];    // per-wave P [q][t]

    int tid = threadIdx.x;
    int wave = tid >> 6, lane = tid & 63;
    int l15 = lane & 15, l16 = lane >> 4;
    int bh = blockIdx.y, b = bh >> 4, h = bh & 15;
    int s0 = blockIdx.x * 128 + wave * 32;

    bf16x8 bfq0 = {0,0,0,0,0,0,0,0};
    bf16x8 bfq1 = {0,0,0,0,0,0,0,0};
    if (l16 == 0) {
        bfq0 = *(const bf16x8*)(qfb + ((size_t)bh * SS + s0 + l15) * 8);
        bfq1 = *(const bf16x8*)(qfb + ((size_t)bh * SS + s0 + 16 + l15) * 8);
    }

    const unsigned short* kfB = kfb + (size_t)bh * SS * 8;
    const unsigned short* vtB = Vt + (size_t)bh * HDD * SS;

    int vd = tid >> 2, vseg = (tid & 3) * 16;

    f32x4 acc[2][4] = {};
    float lsum[2] = {0.f, 0.f};

    for (int t0 = 0; t0 < SS; t0 += 64) {
        __syncthreads();
        {
            const unsigned short* src = vtB + (size_t)vd * SS + t0 + vseg;
            uint4 v0 = *(const uint4*)src;
            uint4 v1 = *(const uint4*)(src + 8);
            *(uint4*)&vt[vd][vseg]     = v0;
            *(uint4*)&vt[vd][vseg + 8] = v1;
        }
        __syncthreads();

        #pragma unroll
        for (int tb = 0; tb < 4; tb++) {
            bf16x8 af = *(const bf16x8*)(kfB + (size_t)(t0 + tb * 16 + l15) * 8);
            #pragma unroll
            for (int qg = 0; qg < 2; qg++) {
                f32x4 sc = {};
                sc = __builtin_amdgcn_mfma_f32_16x16x32_bf16(af, qg ? bfq1 : bfq0, sc, 0, 0, 0);
                float p0 = __expf(sc[0]);
                float p1 = __expf(sc[1]);
                float p2 = __expf(sc[2]);
                float p3 = __expf(sc[3]);
                lsum[qg] += (p0 + p1) + (p2 + p3);
                uint2 pw;
                pw.x = f2bf(p0) | ((unsigned)f2bf(p1) << 16);
                pw.y = f2bf(p2) | ((unsigned)f2bf(p3) << 16);
                *(uint2*)&ps[wave][qg * 16 + l15][tb * 16 + l16 * 4] = pw;
            }
        }

        #pragma unroll
        for (int tk = 0; tk < 2; tk++) {
            bf16x8 bv[4];
            #pragma unroll
            for (int nd = 0; nd < 4; nd++)
                bv[nd] = *(const bf16x8*)&vt[nd * 16 + l15][tk * 32 + l16 * 8];
            #pragma unroll
            for (int mq = 0; mq < 2; mq++) {
                bf16x8 ap = *(const bf16x8*)&ps[wave][mq * 16 + l15][tk * 32 + l16 * 8];
                #pragma unroll
                for (int nd = 0; nd < 4; nd++)
                    acc[mq][nd] = __builtin_amdgcn_mfma_f32_16x16x32_bf16(ap, bv[nd], acc[mq][nd], 0, 0, 0);
            }
        }
    }

    #pragma unroll
    for (int qg = 0; qg < 2; qg++) {
        float v = lsum[qg];
        v += __shfl_xor(v, 16, 64);
        v += __shfl_xor(v, 32, 64);
        lsum[qg] = v;
    }

    #pragma unroll
    for (int mq = 0; mq < 2; mq++) {
        float linv[4];
        #pragma unroll
        for (int r = 0; r < 4; r++)
            linv[r] = 1.f / __shfl(lsum[mq], l16 * 4 + r, 64);
        #pragma unroll
        for (int r = 0; r < 4; r++) {
            int q = s0 + mq * 16 + l16 * 4 + r;
            size_t row = (size_t)(b * SS + q) * HH + h * HDD;
            #pragma unroll
            for (int nd = 0; nd < 4; nd++)
                attnb[row + nd * 16 + l15] = f2bf(acc[mq][nd][r] * linv[r]);
        }
    }
}

extern "C" void kernel_launch(void* const* d_in, const int* in_sizes, int n_in,
                              void* d_out, int out_size, void* d_ws, size_t ws_size,
                              hipStream_t stream)
{
    const float* x  = (const float*)d_in[0];
    const float* Wq = (const float*)d_in[1];
    const float* Wk = (const float*)d_in[2];
    const float* Wv = (const float*)d_in[3];
    const float* Wo = (const float*)d_in[4];
    const float* bq = (const float*)d_in[5];
    const float* bk = (const float*)d_in[6];
    const float* bv = (const float*)d_in[7];
    const float* bo = (const float*)d_in[8];

    // workspace (30 MB total)
    unsigned short* qfb   = (unsigned short*)d_ws;     // 524288
    unsigned short* kfb   = qfb + 524288;              // 524288
    unsigned short* xb    = kfb + 524288;              // 4194304 (aliased w/ attnb)
    unsigned short* attnb = xb;                        // alias: xb dead after V-GEMM
    unsigned short* Wvb   = xb + 4194304;              // 1048576
    unsigned short* Wob   = Wvb + 1048576;             // 1048576
    unsigned short* Vb    = Wob + 1048576;             // 4194304
    unsigned short* Vt    = Vb + 4194304;              // 4194304
    // wsel/bsel live in the Vb region (dead until the V-GEMM, which runs after qk_gemm)
    unsigned short* wselb  = Vb;                       // 65536 shorts
    float*          bselws = (float*)(Vb + 65536);     // 64 floats

    cvt_kernel<<<2112, 256, 0, stream>>>(x, Wv, Wo, Wq, Wk, bq, bk, xb, Wvb, Wob, wselb, bselws);
    qk_gemm_kernel<<<128, 256, 0, stream>>>(xb, wselb, bselws, qfb, kfb);
    gemm_mfma<1><<<dim3(16, 32), 256, 0, stream>>>(xb, Wvb, bv, Vb);
    transpose_v<<<dim3(32, 32), 256, 0, stream>>>(Vb, Vt);
    attn_mfma<<<dim3(16, 32), 256, 0, stream>>>(qfb, kfb, Vt, attnb);
    gemm_mfma<0><<<dim3(16, 32), 256, 0, stream>>>(attnb, Wob, bo, (float*)d_out);
}